// Round 16
// baseline (82.401 us; speedup 1.0000x reference)
//
#include <hip/hip_runtime.h>
#include <math.h>

// Problem constants: B=8, N=4096, C=768, H=W=64, GROUPS=4.
#define BB 8
#define CC 768
#define HH 64
#define WW 64
#define NN 4096
#define GG 4
#define NCHUNK 6
#define CHUNK 128   /* channels per A1 block */

typedef __attribute__((ext_vector_type(8))) _Float16 half8;
typedef __attribute__((ext_vector_type(4))) float f32x4;

// tanh-form GELU approx: v * sigmoid(1.5957691*v*(1+0.044715*v^2)).
__device__ __forceinline__ float gelu_fast(float v) {
    const float z = 1.5957691216f * v * fmaf(0.044715f, v * v, 1.0f);
    return __fdividef(v, 1.0f + __expf(-z));
}

// ---------------------------------------------------------------------------
// A1 = r14 dataflow with the outer batch loop NOT unrolled (I-cache fix).
// All prior variants (r9-r15) fully unrolled the 8-batch sliding-window body
// to ~20-30KB of code -> L1I thrash is the one constant matching the
// "VALU 35-45%, HBM low, no resource limit, occupancy ~30%" signature.
// Here: #pragma unroll 1 on wb, pointer bumps (rT/rM/rB += 8*CC), MFMA
// phase under if(wb&1) with q=wb>>1. Inner j-loops stay unrolled (register
// arrays need compile-time indices). Body ~3KB.
// Structure otherwise identical to r14: block = (b, row h, chunk of 128ch),
// 128 thr (2 waves), grid 3072, XCD-slab swizzle, wave0 = gelu x off_w,
// wave1 = center-x x wt_w, fp16 staging gl/xh[16][144], immediate stores.
// ---------------------------------------------------------------------------
__global__ __launch_bounds__(128, 4) void dq_conv_mfma(
    const float* __restrict__ x,      // (B, N, C)
    const float* __restrict__ dw_w,   // (C, 9)
    const float* __restrict__ dw_b,   // (C,)
    const float* __restrict__ off_w,  // (8, C)
    const float* __restrict__ wt_w,   // (8, C)
    float* __restrict__ offpart)      // (NCHUNK, 16, B*N)
{
    __shared__ __attribute__((aligned(16))) _Float16 gl[16][144];  // 4.6 KB
    __shared__ __attribute__((aligned(16))) _Float16 xh[16][144];  // 4.6 KB
    const int t = threadIdx.x;
    const int lane = t & 63, wv = t >> 6;
    // ---- XCD-slab swizzle (bijective on 3072 = 8 xcd x 64 rows x 6 chunks) ----
    const int xcd = blockIdx.x & 7;
    const int local = blockIdx.x >> 3;         // 0..383
    const int chunk = local % NCHUNK;
    const int r = xcd * (BB * HH / 8) + local / NCHUNK;   // global row 0..511
    const int h = r & (HH - 1);
    const int b = r >> 6;
    const int c = chunk * CHUNK + t;

    // ---- B fragments (fp16): wave0 = off_w, wave1 = wt_w (cols n<8 valid) ----
    const int n = lane & 15, kg = lane >> 4;
    const float* wsrc = (wv == 0) ? off_w : wt_w;
    half8 bfrag[4];
#pragma unroll
    for (int kt = 0; kt < 4; ++kt) {
        const bool valid = (n < 8);
        const float* src = wsrc + (valid ? n : 0) * CC + chunk * CHUNK + kt * 32 + kg * 8;
        half8 bf;
#pragma unroll
        for (int j = 0; j < 8; ++j) {
            bf[j] = (_Float16)(valid ? src[j] : 0.f);
        }
        bfrag[kt] = bf;
    }

    float w9[9];
#pragma unroll
    for (int j = 0; j < 9; ++j) w9[j] = dw_w[c * 9 + j];
    const float bias = dw_b[c];
    const bool tv = (h > 0), bv = (h < HH - 1);
    // boundary rows: clamp pointer, zero the tap weights (no per-load selects)
    const float wt0 = tv ? w9[0] : 0.f, wt1 = tv ? w9[1] : 0.f, wt2 = tv ? w9[2] : 0.f;
    const float wb0 = bv ? w9[6] : 0.f, wb1 = bv ? w9[7] : 0.f, wb2 = bv ? w9[8] : 0.f;

    const float* base = x + (size_t)b * NN * CC + c;
    const float* rT = base + (size_t)((tv ? h - 1 : 0) * WW) * CC;   // h-1 (clamped)
    const float* rM = base + (size_t)(h * WW) * CC;                  // h
    const float* rB = base + (size_t)((bv ? h + 1 : h) * WW) * CC;   // h+1 (clamped)

    float cT[8], cM[8], cB[8], nT[8], nM[8], nB[8];
    float pT = 0.f, pM = 0.f, pB = 0.f;   // column w-1 carries

#pragma unroll
    for (int j = 0; j < 8; ++j) {
        const size_t o = (size_t)j * CC;
        cT[j] = rT[o]; cM[j] = rM[o]; cB[j] = rB[o];
    }

#pragma unroll 1
    for (int wb = 0; wb < 8; ++wb) {
        if (wb < 7) {
#pragma unroll
            for (int j = 0; j < 8; ++j) {
                const size_t o = (size_t)(8 + j) * CC;
                nT[j] = rT[o]; nM[j] = rM[o]; nB[j] = rB[o];
            }
        } else {
#pragma unroll
            for (int j = 0; j < 8; ++j) { nT[j] = 0.f; nM[j] = 0.f; nB[j] = 0.f; }
        }
#pragma unroll
        for (int j = 0; j < 8; ++j) {
            const float lT = j ? cT[j - 1] : pT;
            const float lM = j ? cM[j - 1] : pM;
            const float lB = j ? cB[j - 1] : pB;
            const float rTv = (j == 7) ? nT[0] : cT[j + 1];
            const float rMv = (j == 7) ? nM[0] : cM[j + 1];
            const float rBv = (j == 7) ? nB[0] : cB[j + 1];
            const float conv = lT * wt0 + cT[j] * wt1 + rTv * wt2
                             + lM * w9[3] + cM[j] * w9[4] + rMv * w9[5]
                             + lB * wb0 + cB[j] * wb1 + rBv * wb2;
            const int colq = ((wb & 1) << 3) + j;   // column within quarter
            gl[colq][t] = (_Float16)gelu_fast(conv + bias);
            xh[colq][t] = (_Float16)cM[j];
        }
        pT = cT[7]; pM = cM[7]; pB = cB[7];
#pragma unroll
        for (int j = 0; j < 8; ++j) { cT[j] = nT[j]; cM[j] = nM[j]; cB[j] = nB[j]; }
        rT += 8 * CC; rM += 8 * CC; rB += 8 * CC;

        if (wb & 1) {                    // end of 16-col quarter q = wb>>1
            const int q = wb >> 1;
            __syncthreads();
            f32x4 acc = {0.f, 0.f, 0.f, 0.f};
            if (wv == 0) {
#pragma unroll
                for (int kt = 0; kt < 4; ++kt) {
                    const half8 a = *(const half8*)&gl[n][kt * 32 + kg * 8];
                    acc = __builtin_amdgcn_mfma_f32_16x16x32_f16(a, bfrag[kt], acc, 0, 0, 0);
                }
            } else {
#pragma unroll
                for (int kt = 0; kt < 4; ++kt) {
                    const half8 a = *(const half8*)&xh[n][kt * 32 + kg * 8];
                    acc = __builtin_amdgcn_mfma_f32_16x16x32_f16(a, bfrag[kt], acc, 0, 0, 0);
                }
            }
            // D: col n = plane (n<8 valid), rows kg*4..+3 = 4 consecutive positions
            if (n < 8) {
                const int plane = chunk * 16 + (wv ? 8 + n : n);
                const size_t gpos = (size_t)(b * NN) + h * WW + q * 16 + kg * 4;
                float4 st; st.x = acc[0]; st.y = acc[1]; st.z = acc[2]; st.w = acc[3];
                *(float4*)&offpart[(size_t)plane * (BB * NN) + gpos] = st;
            }
            if (wb < 7) __syncthreads();
        }
    }
}

// ---------------------------------------------------------------------------
// Combine (coalesced): sum 6 chunk partials, sigmoid gate, shift, clip.
// thread: o = t>>5 (0..7), pos = blk*32 + (t&31)  -> gpos-coalesced reads.
// ---------------------------------------------------------------------------
__global__ __launch_bounds__(256) void dq_combine(
    const float* __restrict__ offpart,  // (NCHUNK, 16, B*N)
    const float* __restrict__ off_b,
    const float* __restrict__ wt_b,
    float* __restrict__ ixiy)           // (2, B*G, N)
{
    const int t = threadIdx.x;
    const int o = t >> 5;
    const int gpos = blockIdx.x * 32 + (t & 31);
    const int b = gpos >> 12;
    const int hw = gpos & 4095;
    const int h = hw >> 6, w = hw & 63;

    float so = 0.f, sw = 0.f;
#pragma unroll
    for (int ch = 0; ch < NCHUNK; ++ch) {
        so += offpart[((size_t)(ch * 16 + o)) * (BB * NN) + gpos];
        sw += offpart[((size_t)(ch * 16 + 8 + o)) * (BB * NN) + gpos];
    }
    const float sig = 1.f / (1.f + __expf(-(sw + wt_b[o])));
    const float val = (so + off_b[o]) * sig;

    if (o < 4) {
        const float shx = (o == 2) ? -1.f : ((o == 3) ? 1.f : 0.f);
        const float ix = fminf(fmaxf((float)w + val + shx, 0.f), (float)(WW - 1));
        ixiy[(b * GG + o) * NN + hw] = ix;
    } else {
        const int g = o - 4;
        const float shy = (g == 0) ? -1.f : ((g == 1) ? 1.f : 0.f);
        const float iy = fminf(fmaxf((float)h + val + shy, 0.f), (float)(HH - 1));
        ixiy[BB * GG * NN + (b * GG + g) * NN + hw] = iy;
    }
}

// ---------------------------------------------------------------------------
// B: bilinear border sampling, float4-vectorized, XCD-swizzled (T1).
// 192 threads, 4 ch/thread; 8 coord loads per block broadcast via LDS.
// ---------------------------------------------------------------------------
__global__ __launch_bounds__(192) void dq_sample_vec(
    const float* __restrict__ x,        // (B, N, C)
    const float* __restrict__ ixiy,     // (2, B*G, N)
    float* __restrict__ out)            // (B, N, C)
{
    __shared__ float ixy[8];            // ix[4], iy[4]
    const int t = threadIdx.x;
    // XCD-aware bijective swizzle: 32768 blocks % 8 XCDs == 0; each XCD walks
    // a contiguous chunk of positions -> bilinear rows stay L2-resident.
    const int p = (blockIdx.x & 7) * (BB * NN / 8) + (blockIdx.x >> 3);
    const int b = p >> 12;
    const int hw = p & 4095;

    if (t < 8) {
        const int g = t & 3;
        const int plane = (t >> 2) * (BB * GG * NN);
        ixy[t] = ixiy[plane + (b * GG + g) * NN + hw];
    }
    __syncthreads();

    const int g = t / 48;               // 48 threads x 4ch = 192 ch per group
    const float ix = ixy[g], iy = ixy[4 + g];
    const float x0f = floorf(ix), y0f = floorf(iy);
    const float wx = ix - x0f, wy = iy - y0f;
    const int x0 = (int)x0f, y0 = (int)y0f;
    const int x1 = min(x0 + 1, WW - 1), y1 = min(y0 + 1, HH - 1);
    const int c4 = t * 4;
    const float* xb = x + (size_t)b * NN * CC;
    const float4 v00 = *(const float4*)(xb + (size_t)(y0 * WW + x0) * CC + c4);
    const float4 v01 = *(const float4*)(xb + (size_t)(y0 * WW + x1) * CC + c4);
    const float4 v10 = *(const float4*)(xb + (size_t)(y1 * WW + x0) * CC + c4);
    const float4 v11 = *(const float4*)(xb + (size_t)(y1 * WW + x1) * CC + c4);
    const float w00 = (1.f - wx) * (1.f - wy), w01 = wx * (1.f - wy);
    const float w10 = (1.f - wx) * wy,         w11 = wx * wy;
    float4 r;
    r.x = v00.x * w00 + v01.x * w01 + v10.x * w10 + v11.x * w11;
    r.y = v00.y * w00 + v01.y * w01 + v10.y * w10 + v11.y * w11;
    r.z = v00.z * w00 + v01.z * w01 + v10.z * w10 + v11.z * w11;
    r.w = v00.w * w00 + v01.w * w01 + v10.w * w10 + v11.w * w11;
    *(float4*)(out + (size_t)p * CC + c4) = r;
}

// ---------------------------------------------------------------------------
// Fallback (small ws): round-1 fused offsets kernel + scalar sampler.
// ---------------------------------------------------------------------------
__global__ __launch_bounds__(256) void dqshift_offsets_kernel(
    const float* __restrict__ x, const float* __restrict__ dw_w,
    const float* __restrict__ dw_b, const float* __restrict__ off_w,
    const float* __restrict__ off_b, const float* __restrict__ wt_w,
    const float* __restrict__ wt_b, float* __restrict__ ixiy)
{
    const int wave = threadIdx.x >> 6;
    const int lane = threadIdx.x & 63;
    const int p = blockIdx.x * 4 + wave;
    const int b = p >> 12;
    const int hw = p & 4095;
    const int h = hw >> 6;
    const int w = hw & 63;
    const float* xb = x + (size_t)b * NN * CC;
    float accO[8], accW[8];
#pragma unroll
    for (int o = 0; o < 8; ++o) { accO[o] = 0.f; accW[o] = 0.f; }
    for (int k = 0; k < CC / 64; ++k) {
        const int c = lane + (k << 6);
        float conv = 0.f, xc = 0.f;
#pragma unroll
        for (int dy = -1; dy <= 1; ++dy) {
            const int hh = h + dy;
            const bool vy = (hh >= 0) && (hh < HH);
#pragma unroll
            for (int dx = -1; dx <= 1; ++dx) {
                const int ww = w + dx;
                const bool vv = vy && (ww >= 0) && (ww < WW);
                const float tt = vv ? xb[(size_t)(hh * WW + ww) * CC + c] : 0.f;
                if (dy == 0 && dx == 0) xc = tt;
                conv = fmaf(tt, dw_w[c * 9 + (dy + 1) * 3 + (dx + 1)], conv);
            }
        }
        const float gv = conv + dw_b[c];
        const float gle = 0.5f * gv * (1.0f + erff(gv * 0.70710678118654752f));
#pragma unroll
        for (int o = 0; o < 8; ++o) {
            accO[o] = fmaf(gle, off_w[o * CC + c], accO[o]);
            accW[o] = fmaf(xc, wt_w[o * CC + c], accW[o]);
        }
    }
#pragma unroll
    for (int o = 0; o < 8; ++o) {
#pragma unroll
        for (int s = 32; s > 0; s >>= 1) {
            accO[o] += __shfl_xor(accO[o], s, 64);
            accW[o] += __shfl_xor(accW[o], s, 64);
        }
    }
    if (lane == 0) {
        const float shx[4] = {0.f, 0.f, -1.f, 1.f};
        const float shy[4] = {-1.f, 1.f, 0.f, 0.f};
#pragma unroll
        for (int g = 0; g < 4; ++g) {
            const float sx = 1.f / (1.f + expf(-(accW[g] + wt_b[g])));
            const float sy = 1.f / (1.f + expf(-(accW[4 + g] + wt_b[4 + g])));
            const float ox = (accO[g] + off_b[g]) * sx + shx[g];
            const float oy = (accO[4 + g] + off_b[4 + g]) * sy + shy[g];
            const float ix = fminf(fmaxf((float)w + ox, 0.f), (float)(WW - 1));
            const float iy = fminf(fmaxf((float)h + oy, 0.f), (float)(HH - 1));
            const int idx = (b * GG + g) * NN + hw;
            ixiy[idx] = ix;
            ixiy[BB * GG * NN + idx] = iy;
        }
    }
}

__global__ __launch_bounds__(256) void dqshift_sample_kernel(
    const float* __restrict__ x,
    const float* __restrict__ ixiy,
    float* __restrict__ out)
{
    const int p = blockIdx.x;
    const int b = p >> 12;
    const int hw = p & 4095;
    const float* xb = x + (size_t)b * NN * CC;
    float* ob = out + (size_t)p * CC;

#pragma unroll
    for (int k = 0; k < 3; ++k) {
        const int c = threadIdx.x + (k << 8);
        const int g = c / (CC / GG);
        const int idx = (b * GG + g) * NN + hw;
        const float ix = ixiy[idx];
        const float iy = ixiy[BB * GG * NN + idx];
        const float x0f = floorf(ix);
        const float y0f = floorf(iy);
        const float wx = ix - x0f;
        const float wy = iy - y0f;
        const int x0 = (int)x0f;
        const int y0 = (int)y0f;
        const int x1 = min(x0 + 1, WW - 1);
        const int y1 = min(y0 + 1, HH - 1);
        const float* r0 = xb + (size_t)(y0 * WW) * CC + c;
        const float* r1 = xb + (size_t)(y1 * WW) * CC + c;
        const float v00 = r0[(size_t)x0 * CC];
        const float v01 = r0[(size_t)x1 * CC];
        const float v10 = r1[(size_t)x0 * CC];
        const float v11 = r1[(size_t)x1 * CC];
        ob[c] = v00 * (1.f - wx) * (1.f - wy) + v01 * wx * (1.f - wy)
              + v10 * (1.f - wx) * wy + v11 * wx * wy;
    }
}

extern "C" void kernel_launch(void* const* d_in, const int* in_sizes, int n_in,
                              void* d_out, int out_size, void* d_ws, size_t ws_size,
                              hipStream_t stream) {
    const float* x     = (const float*)d_in[0];
    const float* dw_w  = (const float*)d_in[1];
    const float* dw_b  = (const float*)d_in[2];
    const float* off_w = (const float*)d_in[3];
    const float* off_b = (const float*)d_in[4];
    const float* wt_w  = (const float*)d_in[5];
    const float* wt_b  = (const float*)d_in[6];

    float* ixiy = (float*)d_ws;                              // 1 MiB
    float* offpart = (float*)d_ws + 2 * BB * GG * NN;        // 12.58 MiB
    const size_t need = (size_t)(2 * BB * GG * NN + NCHUNK * 16 * BB * NN) * 4;

    if (ws_size >= need) {
        dq_conv_mfma<<<BB * HH * NCHUNK, 128, 0, stream>>>(
            x, dw_w, dw_b, off_w, wt_w, offpart);
        dq_combine<<<BB * NN / 32, 256, 0, stream>>>(
            offpart, off_b, wt_b, ixiy);
        dq_sample_vec<<<BB * NN, 192, 0, stream>>>(
            x, ixiy, (float*)d_out);
    } else {
        dqshift_offsets_kernel<<<BB * NN / 4, 256, 0, stream>>>(
            x, dw_w, dw_b, off_w, off_b, wt_w, wt_b, ixiy);
        dqshift_sample_kernel<<<BB * NN, 256, 0, stream>>>(x, ixiy, (float*)d_out);
    }
}

// Round 17
// 78.361 us; speedup vs baseline: 1.0516x; 1.0516x over previous
//
#include <hip/hip_runtime.h>
#include <math.h>

// Problem constants: B=8, N=4096, C=768, H=W=64, GROUPS=4.
#define BB 8
#define CC 768
#define HH 64
#define WW 64
#define NN 4096
#define GG 4
#define NCHUNK 6
#define CHUNK 128   /* channels per A1 block */

typedef __attribute__((ext_vector_type(8))) _Float16 half8;
typedef __attribute__((ext_vector_type(4))) float f32x4;

// tanh-form GELU, exp2-folded: v * sigmoid(1.5957691*v*(1+0.044715*v^2)).
// v_exp_f32 natively computes 2^x, so fold log2(e) into the constant:
// 1.5957691 * 1.4426950 = 2.3022223. Saves the mul inside __expf.
__device__ __forceinline__ float gelu_fast(float v) {
    const float z2 = 2.3022223f * v * fmaf(0.044715f, v * v, 1.0f);
    const float e = __builtin_amdgcn_exp2f(-z2);
    return __fdividef(v, 1.0f + e);
}

// ---------------------------------------------------------------------------
// A1 = r14 (fp16, wave-specialized, XCD-slab, fully unrolled — best stable
// config) + double-buffered LDS: gl/xh[2][16][144] = 18.4KB, ONE barrier per
// 16-col quarter instead of two (staging of quarter q+1 writes buf (q+1)&1,
// never the buffer being read; writes to buf q&1 recur only in quarter q+2,
// which is after barrier q+1 — by then all waves' reads of it completed).
// Barrier count 8 -> 4 per block. r12 bundled this with a fatal global
// gather; this isolates it. LDS size is excluded as a limiter (9.2KB
// variants showed the same ~30% occupancy).
// Structure: block = (b, row h, chunk of 128 ch), 128 thr (2 waves),
// grid 3072, XCD-slab swizzle. Wave0 = gelu x off_w (planes n<8),
// wave1 = center-x x wt_w (planes 8+n). Stores immediate per-quarter
// (r8/r13: deferred accs or tight launch_bounds spill; WRITE_SIZE = tell).
// ---------------------------------------------------------------------------
__global__ __launch_bounds__(128, 4) void dq_conv_mfma(
    const float* __restrict__ x,      // (B, N, C)
    const float* __restrict__ dw_w,   // (C, 9)
    const float* __restrict__ dw_b,   // (C,)
    const float* __restrict__ off_w,  // (8, C)
    const float* __restrict__ wt_w,   // (8, C)
    float* __restrict__ offpart)      // (NCHUNK, 16, B*N)
{
    __shared__ __attribute__((aligned(16))) _Float16 gl[2][16][144];  // 9.2 KB
    __shared__ __attribute__((aligned(16))) _Float16 xh[2][16][144];  // 9.2 KB
    const int t = threadIdx.x;
    const int lane = t & 63, wv = t >> 6;
    // ---- XCD-slab swizzle (bijective on 3072 = 8 xcd x 64 rows x 6 chunks) ----
    const int xcd = blockIdx.x & 7;
    const int local = blockIdx.x >> 3;         // 0..383
    const int chunk = local % NCHUNK;
    const int r = xcd * (BB * HH / 8) + local / NCHUNK;   // global row 0..511
    const int h = r & (HH - 1);
    const int b = r >> 6;
    const int c = chunk * CHUNK + t;

    // ---- B fragments (fp16): wave0 = off_w, wave1 = wt_w (cols n<8 valid) ----
    const int n = lane & 15, kg = lane >> 4;
    const float* wsrc = (wv == 0) ? off_w : wt_w;
    half8 bfrag[4];
#pragma unroll
    for (int kt = 0; kt < 4; ++kt) {
        const bool valid = (n < 8);
        const float* src = wsrc + (valid ? n : 0) * CC + chunk * CHUNK + kt * 32 + kg * 8;
        half8 bf;
#pragma unroll
        for (int j = 0; j < 8; ++j) {
            bf[j] = (_Float16)(valid ? src[j] : 0.f);
        }
        bfrag[kt] = bf;
    }

    float w9[9];
#pragma unroll
    for (int j = 0; j < 9; ++j) w9[j] = dw_w[c * 9 + j];
    const float bias = dw_b[c];
    const bool tv = (h > 0), bv = (h < HH - 1);
    // boundary rows: clamp pointer, zero the tap weights (no per-load selects)
    const float wt0 = tv ? w9[0] : 0.f, wt1 = tv ? w9[1] : 0.f, wt2 = tv ? w9[2] : 0.f;
    const float wb0 = bv ? w9[6] : 0.f, wb1 = bv ? w9[7] : 0.f, wb2 = bv ? w9[8] : 0.f;

    const float* base = x + (size_t)b * NN * CC + c;
    const float* rT = base + (size_t)((tv ? h - 1 : 0) * WW) * CC;   // h-1 (clamped)
    const float* rM = base + (size_t)(h * WW) * CC;                  // h
    const float* rB = base + (size_t)((bv ? h + 1 : h) * WW) * CC;   // h+1 (clamped)

    float cT[8], cM[8], cB[8], nT[8], nM[8], nB[8];
    float pT = 0.f, pM = 0.f, pB = 0.f;   // column w-1 carries

#pragma unroll
    for (int j = 0; j < 8; ++j) {
        const size_t o = (size_t)j * CC;
        cT[j] = rT[o]; cM[j] = rM[o]; cB[j] = rB[o];
    }

#pragma unroll
    for (int q = 0; q < 4; ++q) {
        const int qb = q & 1;
#pragma unroll
        for (int hb = 0; hb < 2; ++hb) {
            const int wb = q * 2 + hb;
            if (wb < 7) {
#pragma unroll
                for (int j = 0; j < 8; ++j) {
                    const size_t o = (size_t)(wb * 8 + 8 + j) * CC;
                    nT[j] = rT[o]; nM[j] = rM[o]; nB[j] = rB[o];
                }
            } else {
#pragma unroll
                for (int j = 0; j < 8; ++j) { nT[j] = 0.f; nM[j] = 0.f; nB[j] = 0.f; }
            }
#pragma unroll
            for (int j = 0; j < 8; ++j) {
                const float lT = j ? cT[j - 1] : pT;
                const float lM = j ? cM[j - 1] : pM;
                const float lB = j ? cB[j - 1] : pB;
                const float rTv = (j == 7) ? nT[0] : cT[j + 1];
                const float rMv = (j == 7) ? nM[0] : cM[j + 1];
                const float rBv = (j == 7) ? nB[0] : cB[j + 1];
                const float conv = lT * wt0 + cT[j] * wt1 + rTv * wt2
                                 + lM * w9[3] + cM[j] * w9[4] + rMv * w9[5]
                                 + lB * wb0 + cB[j] * wb1 + rBv * wb2;
                const int colq = hb * 8 + j;     // column within quarter
                gl[qb][colq][t] = (_Float16)gelu_fast(conv + bias);
                xh[qb][colq][t] = (_Float16)cM[j];
            }
            pT = cT[7]; pM = cM[7]; pB = cB[7];
#pragma unroll
            for (int j = 0; j < 8; ++j) { cT[j] = nT[j]; cM[j] = nM[j]; cB[j] = nB[j]; }
        }

        __syncthreads();   // buf qb staged; single barrier per quarter
        // wave 0: gelu x off_w; wave 1: center-x x wt_w. A-row = n (col in quarter).
        f32x4 acc = {0.f, 0.f, 0.f, 0.f};
        if (wv == 0) {
#pragma unroll
            for (int kt = 0; kt < 4; ++kt) {
                const half8 a = *(const half8*)&gl[qb][n][kt * 32 + kg * 8];
                acc = __builtin_amdgcn_mfma_f32_16x16x32_f16(a, bfrag[kt], acc, 0, 0, 0);
            }
        } else {
#pragma unroll
            for (int kt = 0; kt < 4; ++kt) {
                const half8 a = *(const half8*)&xh[qb][n][kt * 32 + kg * 8];
                acc = __builtin_amdgcn_mfma_f32_16x16x32_f16(a, bfrag[kt], acc, 0, 0, 0);
            }
        }
        // D: col n = plane (n<8 valid), rows kg*4..+3 = 4 consecutive positions
        if (n < 8) {
            const int plane = chunk * 16 + (wv ? 8 + n : n);
            const size_t gpos = (size_t)(b * NN) + h * WW + q * 16 + kg * 4;
            float4 st; st.x = acc[0]; st.y = acc[1]; st.z = acc[2]; st.w = acc[3];
            *(float4*)&offpart[(size_t)plane * (BB * NN) + gpos] = st;
        }
        // no trailing barrier: next quarter writes buf qb^1; buf qb is next
        // written in quarter q+2, after the next barrier, by which time all
        // waves' reads above have completed (reads precede that barrier).
    }
}

// ---------------------------------------------------------------------------
// Combine (coalesced): sum 6 chunk partials, sigmoid gate, shift, clip.
// thread: o = t>>5 (0..7), pos = blk*32 + (t&31)  -> gpos-coalesced reads.
// ---------------------------------------------------------------------------
__global__ __launch_bounds__(256) void dq_combine(
    const float* __restrict__ offpart,  // (NCHUNK, 16, B*N)
    const float* __restrict__ off_b,
    const float* __restrict__ wt_b,
    float* __restrict__ ixiy)           // (2, B*G, N)
{
    const int t = threadIdx.x;
    const int o = t >> 5;
    const int gpos = blockIdx.x * 32 + (t & 31);
    const int b = gpos >> 12;
    const int hw = gpos & 4095;
    const int h = hw >> 6, w = hw & 63;

    float so = 0.f, sw = 0.f;
#pragma unroll
    for (int ch = 0; ch < NCHUNK; ++ch) {
        so += offpart[((size_t)(ch * 16 + o)) * (BB * NN) + gpos];
        sw += offpart[((size_t)(ch * 16 + 8 + o)) * (BB * NN) + gpos];
    }
    const float sig = 1.f / (1.f + __expf(-(sw + wt_b[o])));
    const float val = (so + off_b[o]) * sig;

    if (o < 4) {
        const float shx = (o == 2) ? -1.f : ((o == 3) ? 1.f : 0.f);
        const float ix = fminf(fmaxf((float)w + val + shx, 0.f), (float)(WW - 1));
        ixiy[(b * GG + o) * NN + hw] = ix;
    } else {
        const int g = o - 4;
        const float shy = (g == 0) ? -1.f : ((g == 1) ? 1.f : 0.f);
        const float iy = fminf(fmaxf((float)h + val + shy, 0.f), (float)(HH - 1));
        ixiy[BB * GG * NN + (b * GG + g) * NN + hw] = iy;
    }
}

// ---------------------------------------------------------------------------
// B: bilinear border sampling, float4-vectorized, XCD-swizzled (T1).
// 192 threads, 4 ch/thread; 8 coord loads per block broadcast via LDS.
// ---------------------------------------------------------------------------
__global__ __launch_bounds__(192) void dq_sample_vec(
    const float* __restrict__ x,        // (B, N, C)
    const float* __restrict__ ixiy,     // (2, B*G, N)
    float* __restrict__ out)            // (B, N, C)
{
    __shared__ float ixy[8];            // ix[4], iy[4]
    const int t = threadIdx.x;
    // XCD-aware bijective swizzle: 32768 blocks % 8 XCDs == 0; each XCD walks
    // a contiguous chunk of positions -> bilinear rows stay L2-resident.
    const int p = (blockIdx.x & 7) * (BB * NN / 8) + (blockIdx.x >> 3);
    const int b = p >> 12;
    const int hw = p & 4095;

    if (t < 8) {
        const int g = t & 3;
        const int plane = (t >> 2) * (BB * GG * NN);
        ixy[t] = ixiy[plane + (b * GG + g) * NN + hw];
    }
    __syncthreads();

    const int g = t / 48;               // 48 threads x 4ch = 192 ch per group
    const float ix = ixy[g], iy = ixy[4 + g];
    const float x0f = floorf(ix), y0f = floorf(iy);
    const float wx = ix - x0f, wy = iy - y0f;
    const int x0 = (int)x0f, y0 = (int)y0f;
    const int x1 = min(x0 + 1, WW - 1), y1 = min(y0 + 1, HH - 1);
    const int c4 = t * 4;
    const float* xb = x + (size_t)b * NN * CC;
    const float4 v00 = *(const float4*)(xb + (size_t)(y0 * WW + x0) * CC + c4);
    const float4 v01 = *(const float4*)(xb + (size_t)(y0 * WW + x1) * CC + c4);
    const float4 v10 = *(const float4*)(xb + (size_t)(y1 * WW + x0) * CC + c4);
    const float4 v11 = *(const float4*)(xb + (size_t)(y1 * WW + x1) * CC + c4);
    const float w00 = (1.f - wx) * (1.f - wy), w01 = wx * (1.f - wy);
    const float w10 = (1.f - wx) * wy,         w11 = wx * wy;
    float4 r;
    r.x = v00.x * w00 + v01.x * w01 + v10.x * w10 + v11.x * w11;
    r.y = v00.y * w00 + v01.y * w01 + v10.y * w10 + v11.y * w11;
    r.z = v00.z * w00 + v01.z * w01 + v10.z * w10 + v11.z * w11;
    r.w = v00.w * w00 + v01.w * w01 + v10.w * w10 + v11.w * w11;
    *(float4*)(out + (size_t)p * CC + c4) = r;
}

// ---------------------------------------------------------------------------
// Fallback (small ws): round-1 fused offsets kernel + scalar sampler.
// ---------------------------------------------------------------------------
__global__ __launch_bounds__(256) void dqshift_offsets_kernel(
    const float* __restrict__ x, const float* __restrict__ dw_w,
    const float* __restrict__ dw_b, const float* __restrict__ off_w,
    const float* __restrict__ off_b, const float* __restrict__ wt_w,
    const float* __restrict__ wt_b, float* __restrict__ ixiy)
{
    const int wave = threadIdx.x >> 6;
    const int lane = threadIdx.x & 63;
    const int p = blockIdx.x * 4 + wave;
    const int b = p >> 12;
    const int hw = p & 4095;
    const int h = hw >> 6;
    const int w = hw & 63;
    const float* xb = x + (size_t)b * NN * CC;
    float accO[8], accW[8];
#pragma unroll
    for (int o = 0; o < 8; ++o) { accO[o] = 0.f; accW[o] = 0.f; }
    for (int k = 0; k < CC / 64; ++k) {
        const int c = lane + (k << 6);
        float conv = 0.f, xc = 0.f;
#pragma unroll
        for (int dy = -1; dy <= 1; ++dy) {
            const int hh = h + dy;
            const bool vy = (hh >= 0) && (hh < HH);
#pragma unroll
            for (int dx = -1; dx <= 1; ++dx) {
                const int ww = w + dx;
                const bool vv = vy && (ww >= 0) && (ww < WW);
                const float tt = vv ? xb[(size_t)(hh * WW + ww) * CC + c] : 0.f;
                if (dy == 0 && dx == 0) xc = tt;
                conv = fmaf(tt, dw_w[c * 9 + (dy + 1) * 3 + (dx + 1)], conv);
            }
        }
        const float gv = conv + dw_b[c];
        const float gle = 0.5f * gv * (1.0f + erff(gv * 0.70710678118654752f));
#pragma unroll
        for (int o = 0; o < 8; ++o) {
            accO[o] = fmaf(gle, off_w[o * CC + c], accO[o]);
            accW[o] = fmaf(xc, wt_w[o * CC + c], accW[o]);
        }
    }
#pragma unroll
    for (int o = 0; o < 8; ++o) {
#pragma unroll
        for (int s = 32; s > 0; s >>= 1) {
            accO[o] += __shfl_xor(accO[o], s, 64);
            accW[o] += __shfl_xor(accW[o], s, 64);
        }
    }
    if (lane == 0) {
        const float shx[4] = {0.f, 0.f, -1.f, 1.f};
        const float shy[4] = {-1.f, 1.f, 0.f, 0.f};
#pragma unroll
        for (int g = 0; g < 4; ++g) {
            const float sx = 1.f / (1.f + expf(-(accW[g] + wt_b[g])));
            const float sy = 1.f / (1.f + expf(-(accW[4 + g] + wt_b[4 + g])));
            const float ox = (accO[g] + off_b[g]) * sx + shx[g];
            const float oy = (accO[4 + g] + off_b[4 + g]) * sy + shy[g];
            const float ix = fminf(fmaxf((float)w + ox, 0.f), (float)(WW - 1));
            const float iy = fminf(fmaxf((float)h + oy, 0.f), (float)(HH - 1));
            const int idx = (b * GG + g) * NN + hw;
            ixiy[idx] = ix;
            ixiy[BB * GG * NN + idx] = iy;
        }
    }
}

__global__ __launch_bounds__(256) void dqshift_sample_kernel(
    const float* __restrict__ x,
    const float* __restrict__ ixiy,
    float* __restrict__ out)
{
    const int p = blockIdx.x;
    const int b = p >> 12;
    const int hw = p & 4095;
    const float* xb = x + (size_t)b * NN * CC;
    float* ob = out + (size_t)p * CC;

#pragma unroll
    for (int k = 0; k < 3; ++k) {
        const int c = threadIdx.x + (k << 8);
        const int g = c / (CC / GG);
        const int idx = (b * GG + g) * NN + hw;
        const float ix = ixiy[idx];
        const float iy = ixiy[BB * GG * NN + idx];
        const float x0f = floorf(ix);
        const float y0f = floorf(iy);
        const float wx = ix - x0f;
        const float wy = iy - y0f;
        const int x0 = (int)x0f;
        const int y0 = (int)y0f;
        const int x1 = min(x0 + 1, WW - 1);
        const int y1 = min(y0 + 1, HH - 1);
        const float* r0 = xb + (size_t)(y0 * WW) * CC + c;
        const float* r1 = xb + (size_t)(y1 * WW) * CC + c;
        const float v00 = r0[(size_t)x0 * CC];
        const float v01 = r0[(size_t)x1 * CC];
        const float v10 = r1[(size_t)x0 * CC];
        const float v11 = r1[(size_t)x1 * CC];
        ob[c] = v00 * (1.f - wx) * (1.f - wy) + v01 * wx * (1.f - wy)
              + v10 * (1.f - wx) * wy + v11 * wx * wy;
    }
}

extern "C" void kernel_launch(void* const* d_in, const int* in_sizes, int n_in,
                              void* d_out, int out_size, void* d_ws, size_t ws_size,
                              hipStream_t stream) {
    const float* x     = (const float*)d_in[0];
    const float* dw_w  = (const float*)d_in[1];
    const float* dw_b  = (const float*)d_in[2];
    const float* off_w = (const float*)d_in[3];
    const float* off_b = (const float*)d_in[4];
    const float* wt_w  = (const float*)d_in[5];
    const float* wt_b  = (const float*)d_in[6];

    float* ixiy = (float*)d_ws;                              // 1 MiB
    float* offpart = (float*)d_ws + 2 * BB * GG * NN;        // 12.58 MiB
    const size_t need = (size_t)(2 * BB * GG * NN + NCHUNK * 16 * BB * NN) * 4;

    if (ws_size >= need) {
        dq_conv_mfma<<<BB * HH * NCHUNK, 128, 0, stream>>>(
            x, dw_w, dw_b, off_w, wt_w, offpart);
        dq_combine<<<BB * NN / 32, 256, 0, stream>>>(
            offpart, off_b, wt_b, ixiy);
        dq_sample_vec<<<BB * NN, 192, 0, stream>>>(
            x, ixiy, (float*)d_out);
    } else {
        dqshift_offsets_kernel<<<BB * NN / 4, 256, 0, stream>>>(
            x, dw_w, dw_b, off_w, off_b, wt_w, wt_b, ixiy);
        dqshift_sample_kernel<<<BB * NN, 256, 0, stream>>>(x, ixiy, (float*)d_out);
    }
}